// Round 1
// baseline (581.333 us; speedup 1.0000x reference)
//
#include <hip/hip_runtime.h>

#define G_MAX 128
#define D_FEAT 64

// Order-preserving float<->uint encoding (no NaNs in this workload).
__device__ __forceinline__ unsigned f2ord(float f) {
    unsigned u = __float_as_uint(f);
    return (u & 0x80000000u) ? ~u : (u | 0x80000000u);
}
__device__ __forceinline__ float ord2f(unsigned e) {
    unsigned u = (e & 0x80000000u) ? (e ^ 0x80000000u) : ~e;
    return __uint_as_float(u);
}

// ws layout (as u32 words), half = 3*G_MAX*D_FEAT + G_MAX = 24704 words:
//   [0      .. 8191 ] e_umin   [8192 .. 16383] e_umax
//   [16384  .. 24575] e_sum    [24576.. 24703] e_cnt
//   [24704  .. 32895] v_umin   [32896.. 41087] v_umax
//   [41088  .. 49279] v_sum    [49280.. 49407] v_cnt

__global__ void init_ws(unsigned* __restrict__ ws32, int total, int half) {
    int i = blockIdx.x * blockDim.x + threadIdx.x;
    if (i >= total) return;
    int local = i % half;
    ws32[i] = (local < G_MAX * D_FEAT) ? 0xFFFFFFFFu : 0u;
}

// Segment stats: min/max (ordered-uint) + sum + count over rows of attr.
// If src_idx != nullptr: seg = batch[src_idx[e]] (edge mode), else seg = batch[e].
__global__ __launch_bounds__(512) void seg_stats(
    const float* __restrict__ attr, const int* __restrict__ src_idx,
    const int* __restrict__ batch, int n,
    unsigned* __restrict__ g_umin, unsigned* __restrict__ g_umax,
    float* __restrict__ g_sum, float* __restrict__ g_cnt)
{
    __shared__ unsigned s_min[G_MAX * D_FEAT];
    __shared__ unsigned s_max[G_MAX * D_FEAT];
    __shared__ float    s_sum[G_MAX * D_FEAT];
    __shared__ float    s_cnt[G_MAX];

    for (int i = threadIdx.x; i < G_MAX * D_FEAT; i += blockDim.x) {
        s_min[i] = 0xFFFFFFFFu;
        s_max[i] = 0u;
        s_sum[i] = 0.0f;
    }
    for (int i = threadIdx.x; i < G_MAX; i += blockDim.x) s_cnt[i] = 0.0f;
    __syncthreads();

    const int lane   = threadIdx.x & 63;
    const int wave   = threadIdx.x >> 6;
    const int nwaves = blockDim.x >> 6;
    const int q = lane >> 4;   // 0..3 : which of 4 rows this lane covers
    const int p = lane & 15;   // 0..15: 4-feature chunk within the row

    int per   = (n + gridDim.x - 1) / gridDim.x;
    int begin = blockIdx.x * per;
    int end   = min(n, begin + per);

    for (int base = begin + wave * 64; base < end; base += nwaves * 64) {
        int e = base + lane;
        bool v = e < end;
        int seg = 0;
        if (v) {
            int i = src_idx ? src_idx[e] : e;
            seg = batch[i];
        }
        if (v) atomicAdd(&s_cnt[seg], 1.0f);

        int nb = min(64, end - base);   // wave-uniform
        for (int k = 0; k < nb; k += 4) {
            int ek = base + k + q;
            bool vk = ek < end;
            float4 val = make_float4(0.f, 0.f, 0.f, 0.f);
            if (vk) val = *reinterpret_cast<const float4*>(&attr[(size_t)ek * D_FEAT + 4 * p]);
            int segk = __shfl(seg, k + q);   // wave-uniform per 16-lane group
            if (vk) {
                #pragma unroll
                for (int j = 0; j < 4; ++j) {
                    int c = (q + j) & 3;           // rotate to avoid bank conflicts
                    float x = (&val.x)[c];
                    int idx = segk * D_FEAT + 4 * p + c;
                    atomicMin(&s_min[idx], f2ord(x));
                    atomicMax(&s_max[idx], f2ord(x));
                    atomicAdd(&s_sum[idx], x);
                }
            }
        }
    }
    __syncthreads();

    // merge block partials into global accumulators
    for (int i = threadIdx.x; i < G_MAX * D_FEAT; i += blockDim.x) {
        unsigned mn = s_min[i], mx = s_max[i];
        float sm = s_sum[i];
        if (mn != 0xFFFFFFFFu) atomicMin(&g_umin[i], mn);
        if (mx != 0u)          atomicMax(&g_umax[i], mx);
        if (sm != 0.0f)        unsafeAtomicAdd(&g_sum[i], sm);
    }
    for (int i = threadIdx.x; i < G_MAX; i += blockDim.x) {
        float c = s_cnt[i];
        if (c != 0.0f) unsafeAtomicAdd(&g_cnt[i], c);
    }
}

// One block per graph: decode stats -> 576-row -> relu(row@W1+b1) -> @W2+b2.
__global__ __launch_bounds__(256) void finalize_mlp(
    const float* __restrict__ g_in,
    const unsigned* __restrict__ ws32,
    const float* __restrict__ W1, const float* __restrict__ b1,
    const float* __restrict__ W2, const float* __restrict__ b2,
    float* __restrict__ out, int n_in, int n_hid, int n_out)
{
    __shared__ float row[576];
    __shared__ float h[256];
    const int gi = blockIdx.x;

    const unsigned* e_umin = ws32;
    const unsigned* e_umax = ws32 + 8192;
    const float*    e_sum  = (const float*)(ws32 + 16384);
    const float*    e_cnt  = (const float*)(ws32 + 24576);
    const unsigned* v_umin = ws32 + 24704;
    const unsigned* v_umax = ws32 + 32896;
    const float*    v_sum  = (const float*)(ws32 + 41088);
    const float*    v_cnt  = (const float*)(ws32 + 49280);

    for (int i = threadIdx.x; i < n_in; i += blockDim.x) {
        float v;
        if (i < D_FEAT) {
            v = g_in[gi * D_FEAT + i];
        } else if (i < 5 * D_FEAT) {
            int s = (i - D_FEAT) >> 6, d = (i - D_FEAT) & 63;
            int idx = gi * D_FEAT + d;
            if (s == 0)      v = ord2f(e_umin[idx]);
            else if (s == 1) v = e_sum[idx] / fmaxf(e_cnt[gi], 1.0f);
            else if (s == 2) v = e_sum[idx];
            else             v = ord2f(e_umax[idx]);
        } else {
            int s = (i - 5 * D_FEAT) >> 6, d = (i - 5 * D_FEAT) & 63;
            int idx = gi * D_FEAT + d;
            if (s == 0)      v = ord2f(v_umin[idx]);
            else if (s == 1) v = v_sum[idx] / fmaxf(v_cnt[gi], 1.0f);
            else if (s == 2) v = v_sum[idx];
            else             v = ord2f(v_umax[idx]);
        }
        row[i] = v;
    }
    __syncthreads();

    for (int j = threadIdx.x; j < n_hid; j += blockDim.x) {
        float acc = b1[j];
        #pragma unroll 8
        for (int k = 0; k < n_in; ++k) acc = fmaf(row[k], W1[k * n_hid + j], acc);
        h[j] = fmaxf(acc, 0.0f);
    }
    __syncthreads();

    for (int j = threadIdx.x; j < n_out; j += blockDim.x) {
        float acc = b2[j];
        #pragma unroll 8
        for (int k = 0; k < n_hid; ++k) acc = fmaf(h[k], W2[k * n_out + j], acc);
        out[gi * n_out + j] = acc;
    }
}

extern "C" void kernel_launch(void* const* d_in, const int* in_sizes, int n_in_args,
                              void* d_out, int out_size, void* d_ws, size_t ws_size,
                              hipStream_t stream) {
    const float* v_attr    = (const float*)d_in[0];
    const int*   edge_pair = (const int*)d_in[1];   // [2, E]; row 0 = src
    const float* e_attr    = (const float*)d_in[2];
    const float* g_in      = (const float*)d_in[3];
    const int*   batch     = (const int*)d_in[4];
    const float* W1        = (const float*)d_in[5];
    const float* b1        = (const float*)d_in[6];
    const float* W2        = (const float*)d_in[7];
    const float* b2        = (const float*)d_in[8];

    int N  = in_sizes[4];
    int E  = in_sizes[1] / 2;
    int nh = in_sizes[6];            // 256
    int no = in_sizes[8];            // 64
    int ni = in_sizes[5] / nh;       // 576
    int G  = in_sizes[3] / D_FEAT;   // 128

    unsigned* ws32 = (unsigned*)d_ws;
    const int half  = 3 * G_MAX * D_FEAT + G_MAX;   // 24704 words
    const int total = 2 * half;

    init_ws<<<(total + 255) / 256, 256, 0, stream>>>(ws32, total, half);

    // edges: seg = batch[src]
    seg_stats<<<256, 512, 0, stream>>>(e_attr, edge_pair, batch, E,
        ws32, ws32 + 8192, (float*)(ws32 + 16384), (float*)(ws32 + 24576));

    // vertices: seg = batch[i]
    seg_stats<<<256, 512, 0, stream>>>(v_attr, nullptr, batch, N,
        ws32 + 24704, ws32 + 32896, (float*)(ws32 + 41088), (float*)(ws32 + 49280));

    finalize_mlp<<<G, 256, 0, stream>>>(g_in, ws32, W1, b1, W2, b2,
        (float*)d_out, ni, nh, no);
}

// Round 2
// 175.119 us; speedup vs baseline: 3.3196x; 3.3196x over previous
//
#include <hip/hip_runtime.h>
#include <math.h>

#define G_MAX 128
#define D 64
#define NB 1024         // blocks for hist/scatter chunking
#define EBPS 8          // edge-gather blocks per graph
#define VBPS 4          // vertex-gather blocks per graph
#define WPB 4           // waves per 256-thread block

// ---------------- K1: edge segment ids + per-block histogram ----------------
__global__ __launch_bounds__(256) void k_eseg_hist(
    const int* __restrict__ src, const int* __restrict__ batch, int E,
    unsigned char* __restrict__ eseg, unsigned* __restrict__ counts /*[G_MAX][NB]*/)
{
    __shared__ unsigned hist[G_MAX];
    for (int i = threadIdx.x; i < G_MAX; i += blockDim.x) hist[i] = 0u;
    __syncthreads();
    int chunk = (E + NB - 1) / NB;
    int begin = blockIdx.x * chunk;
    int end   = min(E, begin + chunk);
    for (int e = begin + threadIdx.x; e < end; e += blockDim.x) {
        int g = batch[src[e]];
        eseg[e] = (unsigned char)g;
        atomicAdd(&hist[g], 1u);
    }
    __syncthreads();
    for (int i = threadIdx.x; i < G_MAX; i += blockDim.x)
        counts[(size_t)i * NB + blockIdx.x] = hist[i];
}

// ------------- K2a: per-graph exclusive scan of NB block counts -------------
__global__ __launch_bounds__(256) void k_scan_counts(
    unsigned* __restrict__ counts, unsigned* __restrict__ gtot)
{
    __shared__ unsigned s[256];
    unsigned* c = counts + (size_t)blockIdx.x * NB;
    int t = threadIdx.x;
    unsigned v0 = c[4*t], v1 = c[4*t+1], v2 = c[4*t+2], v3 = c[4*t+3];
    s[t] = v0 + v1 + v2 + v3;
    __syncthreads();
    for (int off = 1; off < 256; off <<= 1) {
        unsigned x = (t >= off) ? s[t - off] : 0u;
        __syncthreads();
        s[t] += x;
        __syncthreads();
    }
    unsigned base = (t > 0) ? s[t - 1] : 0u;
    c[4*t]   = base;
    c[4*t+1] = base + v0;
    c[4*t+2] = base + v0 + v1;
    c[4*t+3] = base + v0 + v1 + v2;
    if (t == 255) gtot[blockIdx.x] = s[255];
}

// ---- K2b: graph bucket bases (cbase) + vertex ranges via binary search ----
__global__ __launch_bounds__(256) void k_bounds(
    const unsigned* __restrict__ gtot, const int* __restrict__ batch, int N,
    int* __restrict__ cbase, int* __restrict__ vstart)
{
    int t = threadIdx.x;
    if (t == 0) {
        int acc = 0;
        for (int g = 0; g < G_MAX; ++g) { cbase[g] = acc; acc += (int)gtot[g]; }
        cbase[G_MAX] = acc;
    }
    if (t <= G_MAX) {
        int lo = 0, hi = N;
        while (lo < hi) {
            int mid = (lo + hi) >> 1;
            if (batch[mid] < t) lo = mid + 1; else hi = mid;
        }
        vstart[t] = lo;
    }
}

// ---------------- K3: race-free scatter into per-graph buckets --------------
__global__ __launch_bounds__(256) void k_scatter(
    const unsigned char* __restrict__ eseg, const unsigned* __restrict__ counts,
    const int* __restrict__ cbase, int E, int* __restrict__ sorted_eid)
{
    __shared__ unsigned lcur[G_MAX];
    for (int i = threadIdx.x; i < G_MAX; i += blockDim.x)
        lcur[i] = (unsigned)cbase[i] + counts[(size_t)i * NB + blockIdx.x];
    __syncthreads();
    int chunk = (E + NB - 1) / NB;
    int begin = blockIdx.x * chunk;
    int end   = min(E, begin + chunk);
    for (int e = begin + threadIdx.x; e < end; e += blockDim.x) {
        int g = eseg[e];
        unsigned pos = atomicAdd(&lcur[g], 1u);
        sorted_eid[pos] = e;
    }
}

// ---------------- K4/K5: register-accumulated gather reduction --------------
__device__ __forceinline__ float4 f4min(float4 a, float4 b) {
    return make_float4(fminf(a.x,b.x), fminf(a.y,b.y), fminf(a.z,b.z), fminf(a.w,b.w));
}
__device__ __forceinline__ float4 f4max(float4 a, float4 b) {
    return make_float4(fmaxf(a.x,b.x), fmaxf(a.y,b.y), fmaxf(a.z,b.z), fmaxf(a.w,b.w));
}
__device__ __forceinline__ float4 f4add(float4 a, float4 b) {
    return make_float4(a.x+b.x, a.y+b.y, a.z+b.z, a.w+b.w);
}
__device__ __forceinline__ float4 f4shfl_xor(float4 v, int m) {
    return make_float4(__shfl_xor(v.x, m, 64), __shfl_xor(v.y, m, 64),
                       __shfl_xor(v.z, m, 64), __shfl_xor(v.w, m, 64));
}

__global__ __launch_bounds__(256) void k_gather_stats(
    const float* __restrict__ attr, const int* __restrict__ idx /* null => rows contiguous */,
    const int* __restrict__ bounds, int bps,
    float* __restrict__ pmin, float* __restrict__ pmax, float* __restrict__ psum)
{
    __shared__ float lmin[WPB][D], lmax[WPB][D], lsum[WPB][D];
    int g   = blockIdx.x / bps;
    int sub = blockIdx.x - g * bps;
    int start = bounds[g], end = bounds[g + 1];
    int lane = threadIdx.x & 63, w = threadIdx.x >> 6;
    int q = lane >> 4;          // which of 4 rows this lane covers
    int p = lane & 15;          // 4-feature chunk within row
    int wg = sub * WPB + w;     // global wave index within this graph
    int stride = bps * WPB * 4;

    float4 mn = make_float4(INFINITY, INFINITY, INFINITY, INFINITY);
    float4 mx = make_float4(-INFINITY, -INFINITY, -INFINITY, -INFINITY);
    float4 sm = make_float4(0.f, 0.f, 0.f, 0.f);

    for (int e = start + wg * 4 + q; e < end; e += stride) {
        int rid = idx ? idx[e] : e;
        float4 v = *reinterpret_cast<const float4*>(&attr[(size_t)rid * D + p * 4]);
        mn = f4min(mn, v);
        mx = f4max(mx, v);
        sm = f4add(sm, v);
    }
    // reduce the 4 q-groups (row streams) down to q==0 lanes
    mn = f4min(mn, f4shfl_xor(mn, 16)); mn = f4min(mn, f4shfl_xor(mn, 32));
    mx = f4max(mx, f4shfl_xor(mx, 16)); mx = f4max(mx, f4shfl_xor(mx, 32));
    sm = f4add(sm, f4shfl_xor(sm, 16)); sm = f4add(sm, f4shfl_xor(sm, 32));

    if (q == 0) {
        lmin[w][p*4+0] = mn.x; lmin[w][p*4+1] = mn.y; lmin[w][p*4+2] = mn.z; lmin[w][p*4+3] = mn.w;
        lmax[w][p*4+0] = mx.x; lmax[w][p*4+1] = mx.y; lmax[w][p*4+2] = mx.z; lmax[w][p*4+3] = mx.w;
        lsum[w][p*4+0] = sm.x; lsum[w][p*4+1] = sm.y; lsum[w][p*4+2] = sm.z; lsum[w][p*4+3] = sm.w;
    }
    __syncthreads();
    int t = threadIdx.x;
    if (t < D) {
        float a = fminf(fminf(lmin[0][t], lmin[1][t]), fminf(lmin[2][t], lmin[3][t]));
        float b = fmaxf(fmaxf(lmax[0][t], lmax[1][t]), fmaxf(lmax[2][t], lmax[3][t]));
        float c = lsum[0][t] + lsum[1][t] + lsum[2][t] + lsum[3][t];
        size_t o = ((size_t)g * bps + sub) * D + t;
        pmin[o] = a; pmax[o] = b; psum[o] = c;
    }
}

// ---------------- K6: combine partials -> 576-row -> MLP --------------------
__global__ __launch_bounds__(256) void k_finalize_mlp(
    const float* __restrict__ g_in,
    const float* __restrict__ pe_min, const float* __restrict__ pe_max, const float* __restrict__ pe_sum,
    const float* __restrict__ pv_min, const float* __restrict__ pv_max, const float* __restrict__ pv_sum,
    const int* __restrict__ cbase, const int* __restrict__ vstart,
    const float* __restrict__ W1, const float* __restrict__ b1,
    const float* __restrict__ W2, const float* __restrict__ b2,
    float* __restrict__ out, int n_in, int n_hid, int n_out)
{
    __shared__ float row[576];
    __shared__ float h[256];
    int gi = blockIdx.x;
    int t = threadIdx.x;

    if (t < D) {
        float mn = INFINITY, mx = -INFINITY, sm = 0.f;
        #pragma unroll
        for (int s = 0; s < EBPS; ++s) {
            size_t o = ((size_t)gi * EBPS + s) * D + t;
            mn = fminf(mn, pe_min[o]); mx = fmaxf(mx, pe_max[o]); sm += pe_sum[o];
        }
        float cnt = (float)(cbase[gi + 1] - cbase[gi]);
        row[64 + t]       = mn;
        row[128 + t]      = sm / fmaxf(cnt, 1.0f);
        row[192 + t]      = sm;
        row[256 + t]      = mx;

        float vmn = INFINITY, vmx = -INFINITY, vsm = 0.f;
        #pragma unroll
        for (int s = 0; s < VBPS; ++s) {
            size_t o = ((size_t)gi * VBPS + s) * D + t;
            vmn = fminf(vmn, pv_min[o]); vmx = fmaxf(vmx, pv_max[o]); vsm += pv_sum[o];
        }
        float vcnt = (float)(vstart[gi + 1] - vstart[gi]);
        row[320 + t] = vmn;
        row[384 + t] = vsm / fmaxf(vcnt, 1.0f);
        row[448 + t] = vsm;
        row[512 + t] = vmx;

        row[t] = g_in[gi * D + t];
    }
    __syncthreads();

    for (int j = t; j < n_hid; j += blockDim.x) {
        float acc = b1[j];
        #pragma unroll 8
        for (int k = 0; k < n_in; ++k) acc = fmaf(row[k], W1[k * n_hid + j], acc);
        h[j] = fmaxf(acc, 0.0f);
    }
    __syncthreads();

    for (int j = t; j < n_out; j += blockDim.x) {
        float acc = b2[j];
        #pragma unroll 8
        for (int k = 0; k < n_hid; ++k) acc = fmaf(h[k], W2[k * n_out + j], acc);
        out[gi * n_out + j] = acc;
    }
}

extern "C" void kernel_launch(void* const* d_in, const int* in_sizes, int n_in_args,
                              void* d_out, int out_size, void* d_ws, size_t ws_size,
                              hipStream_t stream) {
    const float* v_attr    = (const float*)d_in[0];
    const int*   edge_pair = (const int*)d_in[1];   // [2, E]; row 0 = src
    const float* e_attr    = (const float*)d_in[2];
    const float* g_in      = (const float*)d_in[3];
    const int*   batch     = (const int*)d_in[4];
    const float* W1        = (const float*)d_in[5];
    const float* b1        = (const float*)d_in[6];
    const float* W2        = (const float*)d_in[7];
    const float* b2        = (const float*)d_in[8];

    int N  = in_sizes[4];
    int E  = in_sizes[1] / 2;
    int nh = in_sizes[6];            // 256
    int no = in_sizes[8];            // 64
    int ni = in_sizes[5] / nh;       // 576
    int G  = in_sizes[3] / D;        // 128

    // ---- ws bump allocation (256B aligned) ----
    char* p = (char*)d_ws;
    auto alloc = [&](size_t bytes) {
        char* r = p;
        p += (bytes + 255) & ~(size_t)255;
        return r;
    };
    unsigned char* eseg   = (unsigned char*)alloc((size_t)E);
    unsigned*      counts = (unsigned*)alloc((size_t)G_MAX * NB * 4);
    unsigned*      gtot   = (unsigned*)alloc((size_t)G_MAX * 4);
    int*           cbase  = (int*)alloc((size_t)(G_MAX + 1) * 4);
    int*           vstart = (int*)alloc((size_t)(G_MAX + 1) * 4);
    int*           s_eid  = (int*)alloc((size_t)E * 4);
    float*         pe_min = (float*)alloc((size_t)G_MAX * EBPS * D * 4);
    float*         pe_max = (float*)alloc((size_t)G_MAX * EBPS * D * 4);
    float*         pe_sum = (float*)alloc((size_t)G_MAX * EBPS * D * 4);
    float*         pv_min = (float*)alloc((size_t)G_MAX * VBPS * D * 4);
    float*         pv_max = (float*)alloc((size_t)G_MAX * VBPS * D * 4);
    float*         pv_sum = (float*)alloc((size_t)G_MAX * VBPS * D * 4);

    k_eseg_hist<<<NB, 256, 0, stream>>>(edge_pair, batch, E, eseg, counts);
    k_scan_counts<<<G_MAX, 256, 0, stream>>>(counts, gtot);
    k_bounds<<<1, 256, 0, stream>>>(gtot, batch, N, cbase, vstart);
    k_scatter<<<NB, 256, 0, stream>>>(eseg, counts, cbase, E, s_eid);

    // edges: gather via sorted index list
    k_gather_stats<<<G * EBPS, 256, 0, stream>>>(e_attr, s_eid, cbase, EBPS,
                                                 pe_min, pe_max, pe_sum);
    // vertices: batch is sorted -> contiguous row ranges, no index list
    k_gather_stats<<<G * VBPS, 256, 0, stream>>>(v_attr, nullptr, vstart, VBPS,
                                                 pv_min, pv_max, pv_sum);

    k_finalize_mlp<<<G, 256, 0, stream>>>(g_in,
        pe_min, pe_max, pe_sum, pv_min, pv_max, pv_sum,
        cbase, vstart, W1, b1, W2, b2,
        (float*)d_out, ni, nh, no);
}

// Round 3
// 140.303 us; speedup vs baseline: 4.1434x; 1.2481x over previous
//
#include <hip/hip_runtime.h>
#include <math.h>

#define G_MAX 128
#define D 64
#define NB 1024         // blocks for hist/scatter chunking
#define EBPS 32         // edge-gather blocks per graph  (power of 2)
#define EBPS_SHIFT 5
#define VBPS 8          // vertex-gather blocks per graph (power of 2)
#define VBPS_SHIFT 3
#define WPB 4           // waves per 256-thread block

// ---------------- K1: edge segment ids + per-block histogram ----------------
__global__ __launch_bounds__(256) void k_eseg_hist(
    const int* __restrict__ src, const int* __restrict__ batch, int E,
    unsigned char* __restrict__ eseg, unsigned* __restrict__ counts /*[G_MAX][NB]*/)
{
    __shared__ unsigned hist[G_MAX];
    for (int i = threadIdx.x; i < G_MAX; i += blockDim.x) hist[i] = 0u;
    __syncthreads();
    int chunk = (E + NB - 1) / NB;
    int begin = blockIdx.x * chunk;
    int end   = min(E, begin + chunk);
    for (int e = begin + threadIdx.x; e < end; e += blockDim.x) {
        int g = batch[src[e]];
        eseg[e] = (unsigned char)g;
        atomicAdd(&hist[g], 1u);
    }
    __syncthreads();
    for (int i = threadIdx.x; i < G_MAX; i += blockDim.x)
        counts[(size_t)i * NB + blockIdx.x] = hist[i];
}

// ------------- K2a: per-graph exclusive scan of NB block counts -------------
__global__ __launch_bounds__(256) void k_scan_counts(
    unsigned* __restrict__ counts, unsigned* __restrict__ gtot)
{
    __shared__ unsigned s[256];
    unsigned* c = counts + (size_t)blockIdx.x * NB;
    int t = threadIdx.x;
    unsigned v0 = c[4*t], v1 = c[4*t+1], v2 = c[4*t+2], v3 = c[4*t+3];
    s[t] = v0 + v1 + v2 + v3;
    __syncthreads();
    for (int off = 1; off < 256; off <<= 1) {
        unsigned x = (t >= off) ? s[t - off] : 0u;
        __syncthreads();
        s[t] += x;
        __syncthreads();
    }
    unsigned base = (t > 0) ? s[t - 1] : 0u;
    c[4*t]   = base;
    c[4*t+1] = base + v0;
    c[4*t+2] = base + v0 + v1;
    c[4*t+3] = base + v0 + v1 + v2;
    if (t == 255) gtot[blockIdx.x] = s[255];
}

// ---- K2b: graph bucket bases (cbase) + vertex ranges via binary search ----
__global__ __launch_bounds__(256) void k_bounds(
    const unsigned* __restrict__ gtot, const int* __restrict__ batch, int N,
    int* __restrict__ cbase, int* __restrict__ vstart)
{
    int t = threadIdx.x;
    if (t == 0) {
        int acc = 0;
        for (int g = 0; g < G_MAX; ++g) { cbase[g] = acc; acc += (int)gtot[g]; }
        cbase[G_MAX] = acc;
    }
    if (t <= G_MAX) {
        int lo = 0, hi = N;
        while (lo < hi) {
            int mid = (lo + hi) >> 1;
            if (batch[mid] < t) lo = mid + 1; else hi = mid;
        }
        vstart[t] = lo;
    }
}

// ---------------- K3: race-free scatter into per-graph buckets --------------
__global__ __launch_bounds__(256) void k_scatter(
    const unsigned char* __restrict__ eseg, const unsigned* __restrict__ counts,
    const int* __restrict__ cbase, int E, int* __restrict__ sorted_eid)
{
    __shared__ unsigned lcur[G_MAX];
    for (int i = threadIdx.x; i < G_MAX; i += blockDim.x)
        lcur[i] = (unsigned)cbase[i] + counts[(size_t)i * NB + blockIdx.x];
    __syncthreads();
    int chunk = (E + NB - 1) / NB;
    int begin = blockIdx.x * chunk;
    int end   = min(E, begin + chunk);
    for (int e = begin + threadIdx.x; e < end; e += blockDim.x) {
        int g = eseg[e];
        unsigned pos = atomicAdd(&lcur[g], 1u);
        sorted_eid[pos] = e;
    }
}

// ---------------- K4: combined register-accumulated gather reduction --------
__device__ __forceinline__ float4 f4min(float4 a, float4 b) {
    return make_float4(fminf(a.x,b.x), fminf(a.y,b.y), fminf(a.z,b.z), fminf(a.w,b.w));
}
__device__ __forceinline__ float4 f4max(float4 a, float4 b) {
    return make_float4(fmaxf(a.x,b.x), fmaxf(a.y,b.y), fmaxf(a.z,b.z), fmaxf(a.w,b.w));
}
__device__ __forceinline__ float4 f4add(float4 a, float4 b) {
    return make_float4(a.x+b.x, a.y+b.y, a.z+b.z, a.w+b.w);
}
__device__ __forceinline__ float4 f4shfl_xor(float4 v, int m) {
    return make_float4(__shfl_xor(v.x, m, 64), __shfl_xor(v.y, m, 64),
                       __shfl_xor(v.z, m, 64), __shfl_xor(v.w, m, 64));
}

__global__ __launch_bounds__(256) void k_gather_stats(
    const float* __restrict__ e_attr_, const int* __restrict__ s_eid,
    const int* __restrict__ cbase,
    const float* __restrict__ v_attr_, const int* __restrict__ vstart,
    float* __restrict__ pe_min, float* __restrict__ pe_max, float* __restrict__ pe_sum,
    float* __restrict__ pv_min, float* __restrict__ pv_max, float* __restrict__ pv_sum)
{
    __shared__ float lmin[WPB][D], lmax[WPB][D], lsum[WPB][D];
    const int b = blockIdx.x;
    const bool isE = (b < G_MAX * EBPS);
    const float* attr  = isE ? e_attr_ : v_attr_;
    const int*  idx    = isE ? s_eid : nullptr;
    const int*  bounds = isE ? cbase : vstart;
    float* pmin = isE ? pe_min : pv_min;
    float* pmax = isE ? pe_max : pv_max;
    float* psum = isE ? pe_sum : pv_sum;
    const int bid   = isE ? b : (b - G_MAX * EBPS);
    const int shift = isE ? EBPS_SHIFT : VBPS_SHIFT;
    const int bps   = 1 << shift;
    const int g     = bid >> shift;
    const int sub   = bid & (bps - 1);

    const int start = bounds[g], end = bounds[g + 1];
    const int lane = threadIdx.x & 63, w = threadIdx.x >> 6;
    const int q = lane >> 4;          // which of 4 rows this lane covers
    const int p = lane & 15;          // 4-feature chunk within row
    const int wg = sub * WPB + w;     // global wave index within this graph
    const int stride = bps * WPB * 8; // 8 rows per wave per iteration

    float4 mn = make_float4(INFINITY, INFINITY, INFINITY, INFINITY);
    float4 mx = make_float4(-INFINITY, -INFINITY, -INFINITY, -INFINITY);
    float4 sm = make_float4(0.f, 0.f, 0.f, 0.f);

    for (int e = start + wg * 8 + q; e < end; e += stride) {
        int e2 = e + 4;
        bool ok2 = e2 < end;
        int rid  = idx ? idx[e] : e;
        int rid2 = ok2 ? (idx ? idx[e2] : e2) : rid;
        float4 a  = *reinterpret_cast<const float4*>(&attr[(size_t)rid  * D + p * 4]);
        float4 bb = *reinterpret_cast<const float4*>(&attr[(size_t)rid2 * D + p * 4]);
        mn = f4min(mn, a); mx = f4max(mx, a); sm = f4add(sm, a);
        if (ok2) { mn = f4min(mn, bb); mx = f4max(mx, bb); sm = f4add(sm, bb); }
    }
    // reduce the 4 q-groups (row streams) down to q==0 lanes
    mn = f4min(mn, f4shfl_xor(mn, 16)); mn = f4min(mn, f4shfl_xor(mn, 32));
    mx = f4max(mx, f4shfl_xor(mx, 16)); mx = f4max(mx, f4shfl_xor(mx, 32));
    sm = f4add(sm, f4shfl_xor(sm, 16)); sm = f4add(sm, f4shfl_xor(sm, 32));

    if (q == 0) {
        lmin[w][p*4+0] = mn.x; lmin[w][p*4+1] = mn.y; lmin[w][p*4+2] = mn.z; lmin[w][p*4+3] = mn.w;
        lmax[w][p*4+0] = mx.x; lmax[w][p*4+1] = mx.y; lmax[w][p*4+2] = mx.z; lmax[w][p*4+3] = mx.w;
        lsum[w][p*4+0] = sm.x; lsum[w][p*4+1] = sm.y; lsum[w][p*4+2] = sm.z; lsum[w][p*4+3] = sm.w;
    }
    __syncthreads();
    int t = threadIdx.x;
    if (t < D) {
        float a = fminf(fminf(lmin[0][t], lmin[1][t]), fminf(lmin[2][t], lmin[3][t]));
        float b2 = fmaxf(fmaxf(lmax[0][t], lmax[1][t]), fmaxf(lmax[2][t], lmax[3][t]));
        float c = lsum[0][t] + lsum[1][t] + lsum[2][t] + lsum[3][t];
        size_t o = ((size_t)g * bps + sub) * D + t;
        pmin[o] = a; pmax[o] = b2; psum[o] = c;
    }
}

// ---------------- K6: combine partials -> 576-row -> MLP --------------------
__global__ __launch_bounds__(256) void k_finalize_mlp(
    const float* __restrict__ g_in,
    const float* __restrict__ pe_min, const float* __restrict__ pe_max, const float* __restrict__ pe_sum,
    const float* __restrict__ pv_min, const float* __restrict__ pv_max, const float* __restrict__ pv_sum,
    const int* __restrict__ cbase, const int* __restrict__ vstart,
    const float* __restrict__ W1, const float* __restrict__ b1,
    const float* __restrict__ W2, const float* __restrict__ b2,
    float* __restrict__ out, int n_in, int n_hid, int n_out)
{
    __shared__ float row[576];
    __shared__ float h[256];
    int gi = blockIdx.x;
    int t = threadIdx.x;

    if (t < D) {
        float mn = INFINITY, mx = -INFINITY, sm = 0.f;
        #pragma unroll 8
        for (int s = 0; s < EBPS; ++s) {
            size_t o = ((size_t)gi * EBPS + s) * D + t;
            mn = fminf(mn, pe_min[o]); mx = fmaxf(mx, pe_max[o]); sm += pe_sum[o];
        }
        float cnt = (float)(cbase[gi + 1] - cbase[gi]);
        row[64 + t]  = mn;
        row[128 + t] = sm / fmaxf(cnt, 1.0f);
        row[192 + t] = sm;
        row[256 + t] = mx;

        float vmn = INFINITY, vmx = -INFINITY, vsm = 0.f;
        #pragma unroll 8
        for (int s = 0; s < VBPS; ++s) {
            size_t o = ((size_t)gi * VBPS + s) * D + t;
            vmn = fminf(vmn, pv_min[o]); vmx = fmaxf(vmx, pv_max[o]); vsm += pv_sum[o];
        }
        float vcnt = (float)(vstart[gi + 1] - vstart[gi]);
        row[320 + t] = vmn;
        row[384 + t] = vsm / fmaxf(vcnt, 1.0f);
        row[448 + t] = vsm;
        row[512 + t] = vmx;

        row[t] = g_in[gi * D + t];
    }
    __syncthreads();

    for (int j = t; j < n_hid; j += blockDim.x) {
        float acc = b1[j];
        #pragma unroll 8
        for (int k = 0; k < n_in; ++k) acc = fmaf(row[k], W1[k * n_hid + j], acc);
        h[j] = fmaxf(acc, 0.0f);
    }
    __syncthreads();

    for (int j = t; j < n_out; j += blockDim.x) {
        float acc = b2[j];
        #pragma unroll 8
        for (int k = 0; k < n_hid; ++k) acc = fmaf(h[k], W2[k * n_out + j], acc);
        out[gi * n_out + j] = acc;
    }
}

extern "C" void kernel_launch(void* const* d_in, const int* in_sizes, int n_in_args,
                              void* d_out, int out_size, void* d_ws, size_t ws_size,
                              hipStream_t stream) {
    const float* v_attr    = (const float*)d_in[0];
    const int*   edge_pair = (const int*)d_in[1];   // [2, E]; row 0 = src
    const float* e_attr    = (const float*)d_in[2];
    const float* g_in      = (const float*)d_in[3];
    const int*   batch     = (const int*)d_in[4];
    const float* W1        = (const float*)d_in[5];
    const float* b1        = (const float*)d_in[6];
    const float* W2        = (const float*)d_in[7];
    const float* b2        = (const float*)d_in[8];

    int N  = in_sizes[4];
    int E  = in_sizes[1] / 2;
    int nh = in_sizes[6];            // 256
    int no = in_sizes[8];            // 64
    int ni = in_sizes[5] / nh;       // 576
    int G  = in_sizes[3] / D;        // 128

    // ---- ws bump allocation (256B aligned) ----
    char* p = (char*)d_ws;
    auto alloc = [&](size_t bytes) {
        char* r = p;
        p += (bytes + 255) & ~(size_t)255;
        return r;
    };
    unsigned char* eseg   = (unsigned char*)alloc((size_t)E);
    unsigned*      counts = (unsigned*)alloc((size_t)G_MAX * NB * 4);
    unsigned*      gtot   = (unsigned*)alloc((size_t)G_MAX * 4);
    int*           cbase  = (int*)alloc((size_t)(G_MAX + 1) * 4);
    int*           vstart = (int*)alloc((size_t)(G_MAX + 1) * 4);
    int*           s_eid  = (int*)alloc((size_t)E * 4);
    float*         pe_min = (float*)alloc((size_t)G_MAX * EBPS * D * 4);
    float*         pe_max = (float*)alloc((size_t)G_MAX * EBPS * D * 4);
    float*         pe_sum = (float*)alloc((size_t)G_MAX * EBPS * D * 4);
    float*         pv_min = (float*)alloc((size_t)G_MAX * VBPS * D * 4);
    float*         pv_max = (float*)alloc((size_t)G_MAX * VBPS * D * 4);
    float*         pv_sum = (float*)alloc((size_t)G_MAX * VBPS * D * 4);

    k_eseg_hist<<<NB, 256, 0, stream>>>(edge_pair, batch, E, eseg, counts);
    k_scan_counts<<<G_MAX, 256, 0, stream>>>(counts, gtot);
    k_bounds<<<1, 256, 0, stream>>>(gtot, batch, N, cbase, vstart);
    k_scatter<<<NB, 256, 0, stream>>>(eseg, counts, cbase, E, s_eid);

    // combined edge + vertex gather (edges: via sorted id list; vertices: contiguous)
    k_gather_stats<<<G_MAX * EBPS + G_MAX * VBPS, 256, 0, stream>>>(
        e_attr, s_eid, cbase, v_attr, vstart,
        pe_min, pe_max, pe_sum, pv_min, pv_max, pv_sum);

    k_finalize_mlp<<<G, 256, 0, stream>>>(g_in,
        pe_min, pe_max, pe_sum, pv_min, pv_max, pv_sum,
        cbase, vstart, W1, b1, W2, b2,
        (float*)d_out, ni, nh, no);
}

// Round 6
// 134.315 us; speedup vs baseline: 4.3281x; 1.0446x over previous
//
#include <hip/hip_runtime.h>
#include <math.h>

#define G_MAX 128
#define D 64
#define NB 1024         // blocks for hist/scatter chunking
#define EBPS 32         // edge-gather blocks per graph  (power of 2)
#define EBPS_SHIFT 5
#define VBPS 8          // vertex-gather blocks per graph (power of 2)
#define VBPS_SHIFT 3
#define WPB 4           // waves per 256-thread block

// ---------------- K1: edge segment ids + per-block histogram ----------------
__global__ __launch_bounds__(256) void k_eseg_hist(
    const int* __restrict__ src, const int* __restrict__ batch, int E,
    unsigned char* __restrict__ eseg, unsigned* __restrict__ counts /*[G_MAX][NB]*/)
{
    __shared__ unsigned hist[G_MAX];
    for (int i = threadIdx.x; i < G_MAX; i += blockDim.x) hist[i] = 0u;
    __syncthreads();
    int chunk = (E + NB - 1) / NB;
    int begin = blockIdx.x * chunk;
    int end   = min(E, begin + chunk);
    for (int e = begin + threadIdx.x; e < end; e += blockDim.x) {
        int g = batch[src[e]];
        eseg[e] = (unsigned char)g;
        atomicAdd(&hist[g], 1u);
    }
    __syncthreads();
    for (int i = threadIdx.x; i < G_MAX; i += blockDim.x)
        counts[(size_t)i * NB + blockIdx.x] = hist[i];
}

// ------------- K2a: per-graph exclusive scan of NB block counts -------------
__global__ __launch_bounds__(256) void k_scan_counts(
    unsigned* __restrict__ counts, unsigned* __restrict__ gtot)
{
    __shared__ unsigned s[256];
    unsigned* c = counts + (size_t)blockIdx.x * NB;
    int t = threadIdx.x;
    unsigned v0 = c[4*t], v1 = c[4*t+1], v2 = c[4*t+2], v3 = c[4*t+3];
    s[t] = v0 + v1 + v2 + v3;
    __syncthreads();
    for (int off = 1; off < 256; off <<= 1) {
        unsigned x = (t >= off) ? s[t - off] : 0u;
        __syncthreads();
        s[t] += x;
        __syncthreads();
    }
    unsigned base = (t > 0) ? s[t - 1] : 0u;
    c[4*t]   = base;
    c[4*t+1] = base + v0;
    c[4*t+2] = base + v0 + v1;
    c[4*t+3] = base + v0 + v1 + v2;
    if (t == 255) gtot[blockIdx.x] = s[255];
}

// ---- K2b: graph bucket bases (cbase) + vertex ranges via binary search ----
__global__ __launch_bounds__(256) void k_bounds(
    const unsigned* __restrict__ gtot, const int* __restrict__ batch, int N,
    int* __restrict__ cbase, int* __restrict__ vstart)
{
    int t = threadIdx.x;
    if (t == 0) {
        int acc = 0;
        for (int g = 0; g < G_MAX; ++g) { cbase[g] = acc; acc += (int)gtot[g]; }
        cbase[G_MAX] = acc;
    }
    if (t <= G_MAX) {
        int lo = 0, hi = N;
        while (lo < hi) {
            int mid = (lo + hi) >> 1;
            if (batch[mid] < t) lo = mid + 1; else hi = mid;
        }
        vstart[t] = lo;
    }
}

// ---------------- K3: race-free scatter into per-graph buckets --------------
__global__ __launch_bounds__(256) void k_scatter(
    const unsigned char* __restrict__ eseg, const unsigned* __restrict__ counts,
    const int* __restrict__ cbase, int E, int* __restrict__ sorted_eid)
{
    __shared__ unsigned lcur[G_MAX];
    for (int i = threadIdx.x; i < G_MAX; i += blockDim.x)
        lcur[i] = (unsigned)cbase[i] + counts[(size_t)i * NB + blockIdx.x];
    __syncthreads();
    int chunk = (E + NB - 1) / NB;
    int begin = blockIdx.x * chunk;
    int end   = min(E, begin + chunk);
    for (int e = begin + threadIdx.x; e < end; e += blockDim.x) {
        int g = eseg[e];
        unsigned pos = atomicAdd(&lcur[g], 1u);
        sorted_eid[pos] = e;
    }
}

// ---------------- K4: combined register-accumulated gather reduction --------
__device__ __forceinline__ float4 f4shfl_xor(float4 v, int m) {
    return make_float4(__shfl_xor(v.x, m, 64), __shfl_xor(v.y, m, 64),
                       __shfl_xor(v.z, m, 64), __shfl_xor(v.w, m, 64));
}
__device__ __forceinline__ float4 f4add(float4 a, float4 b) {
    return make_float4(a.x + b.x, a.y + b.y, a.z + b.z, a.w + b.w);
}
__device__ __forceinline__ void acc4(float4 v, float4& mn, float4& mx, float4& sm) {
    mn.x = fminf(mn.x, v.x); mn.y = fminf(mn.y, v.y); mn.z = fminf(mn.z, v.z); mn.w = fminf(mn.w, v.w);
    mx.x = fmaxf(mx.x, v.x); mx.y = fmaxf(mx.y, v.y); mx.z = fmaxf(mx.z, v.z); mx.w = fmaxf(mx.w, v.w);
    sm.x += v.x; sm.y += v.y; sm.z += v.z; sm.w += v.w;
}

__global__ __launch_bounds__(256) void k_gather_stats(
    const float* __restrict__ e_attr_, const int* __restrict__ s_eid,
    const int* __restrict__ cbase,
    const float* __restrict__ v_attr_, const int* __restrict__ vstart,
    float* __restrict__ pe_min, float* __restrict__ pe_max, float* __restrict__ pe_sum,
    float* __restrict__ pv_min, float* __restrict__ pv_max, float* __restrict__ pv_sum)
{
    __shared__ float lmin[WPB][D], lmax[WPB][D], lsum[WPB][D];
    const int b = blockIdx.x;
    const bool isE = (b < G_MAX * EBPS);
    const float* attr  = isE ? e_attr_ : v_attr_;
    const int*  idx    = isE ? s_eid : nullptr;
    const int*  bounds = isE ? cbase : vstart;
    float* pmin = isE ? pe_min : pv_min;
    float* pmax = isE ? pe_max : pv_max;
    float* psum = isE ? pe_sum : pv_sum;
    const int bid   = isE ? b : (b - G_MAX * EBPS);
    const int shift = isE ? EBPS_SHIFT : VBPS_SHIFT;
    const int bps   = 1 << shift;
    const int g     = bid >> shift;
    const int sub   = bid & (bps - 1);

    const int start = bounds[g], end = bounds[g + 1];
    const int lane = threadIdx.x & 63, w = threadIdx.x >> 6;
    const int q = lane >> 4;          // which of 4 row streams this lane covers
    const int p = lane & 15;          // 4-feature chunk within row
    const int wg = sub * WPB + w;     // global wave index within this graph
    const int stride = bps * WPB * 16; // 16 rows per wave per iteration

    float4 mn = make_float4(INFINITY, INFINITY, INFINITY, INFINITY);
    float4 mx = make_float4(-INFINITY, -INFINITY, -INFINITY, -INFINITY);
    float4 sm = make_float4(0.f, 0.f, 0.f, 0.f);

    for (int e = start + wg * 16 + q; e < end; e += stride) {
        int eB = e + 4, eC = e + 8, eD = e + 12;
        bool okB = eB < end, okC = eC < end, okD = eD < end;
        int ridA = idx ? idx[e] : e;
        int ridB = okB ? (idx ? idx[eB] : eB) : ridA;
        int ridC = okC ? (idx ? idx[eC] : eC) : ridA;
        int ridD = okD ? (idx ? idx[eD] : eD) : ridA;
        float4 vA = *reinterpret_cast<const float4*>(&attr[(size_t)ridA * D + p * 4]);
        float4 vB = *reinterpret_cast<const float4*>(&attr[(size_t)ridB * D + p * 4]);
        float4 vC = *reinterpret_cast<const float4*>(&attr[(size_t)ridC * D + p * 4]);
        float4 vD = *reinterpret_cast<const float4*>(&attr[(size_t)ridD * D + p * 4]);
        acc4(vA, mn, mx, sm);
        if (okB) acc4(vB, mn, mx, sm);
        if (okC) acc4(vC, mn, mx, sm);
        if (okD) acc4(vD, mn, mx, sm);
    }

    // reduce the 4 q-groups (row streams) down to q==0 lanes
    float4 o;
    o = f4shfl_xor(mn, 16);
    mn.x = fminf(mn.x, o.x); mn.y = fminf(mn.y, o.y); mn.z = fminf(mn.z, o.z); mn.w = fminf(mn.w, o.w);
    o = f4shfl_xor(mn, 32);
    mn.x = fminf(mn.x, o.x); mn.y = fminf(mn.y, o.y); mn.z = fminf(mn.z, o.z); mn.w = fminf(mn.w, o.w);
    o = f4shfl_xor(mx, 16);
    mx.x = fmaxf(mx.x, o.x); mx.y = fmaxf(mx.y, o.y); mx.z = fmaxf(mx.z, o.z); mx.w = fmaxf(mx.w, o.w);
    o = f4shfl_xor(mx, 32);
    mx.x = fmaxf(mx.x, o.x); mx.y = fmaxf(mx.y, o.y); mx.z = fmaxf(mx.z, o.z); mx.w = fmaxf(mx.w, o.w);
    sm = f4add(sm, f4shfl_xor(sm, 16));
    sm = f4add(sm, f4shfl_xor(sm, 32));

    if (q == 0) {
        lmin[w][p*4+0] = mn.x; lmin[w][p*4+1] = mn.y; lmin[w][p*4+2] = mn.z; lmin[w][p*4+3] = mn.w;
        lmax[w][p*4+0] = mx.x; lmax[w][p*4+1] = mx.y; lmax[w][p*4+2] = mx.z; lmax[w][p*4+3] = mx.w;
        lsum[w][p*4+0] = sm.x; lsum[w][p*4+1] = sm.y; lsum[w][p*4+2] = sm.z; lsum[w][p*4+3] = sm.w;
    }
    __syncthreads();
    int t = threadIdx.x;
    if (t < D) {
        float a  = fminf(fminf(lmin[0][t], lmin[1][t]), fminf(lmin[2][t], lmin[3][t]));
        float b2 = fmaxf(fmaxf(lmax[0][t], lmax[1][t]), fmaxf(lmax[2][t], lmax[3][t]));
        float c  = lsum[0][t] + lsum[1][t] + lsum[2][t] + lsum[3][t];
        size_t o2 = ((size_t)g * bps + sub) * D + t;
        pmin[o2] = a; pmax[o2] = b2; psum[o2] = c;
    }
}

// ---------------- K5: combine partials -> 576-row -> MLP --------------------
__global__ __launch_bounds__(256) void k_finalize_mlp(
    const float* __restrict__ g_in,
    const float* __restrict__ pe_min, const float* __restrict__ pe_max, const float* __restrict__ pe_sum,
    const float* __restrict__ pv_min, const float* __restrict__ pv_max, const float* __restrict__ pv_sum,
    const int* __restrict__ cbase, const int* __restrict__ vstart,
    const float* __restrict__ W1, const float* __restrict__ b1,
    const float* __restrict__ W2, const float* __restrict__ b2,
    float* __restrict__ out, int n_in, int n_hid, int n_out)
{
    __shared__ float row[576];
    __shared__ float h[256];
    int gi = blockIdx.x;
    int t = threadIdx.x;

    if (t < D) {
        float mn = INFINITY, mx = -INFINITY, sm = 0.f;
        #pragma unroll 8
        for (int s = 0; s < EBPS; ++s) {
            size_t o = ((size_t)gi * EBPS + s) * D + t;
            mn = fminf(mn, pe_min[o]); mx = fmaxf(mx, pe_max[o]); sm += pe_sum[o];
        }
        float cnt = (float)(cbase[gi + 1] - cbase[gi]);
        row[64 + t]  = mn;
        row[128 + t] = sm / fmaxf(cnt, 1.0f);
        row[192 + t] = sm;
        row[256 + t] = mx;

        float vmn = INFINITY, vmx = -INFINITY, vsm = 0.f;
        #pragma unroll 8
        for (int s = 0; s < VBPS; ++s) {
            size_t o = ((size_t)gi * VBPS + s) * D + t;
            vmn = fminf(vmn, pv_min[o]); vmx = fmaxf(vmx, pv_max[o]); vsm += pv_sum[o];
        }
        float vcnt = (float)(vstart[gi + 1] - vstart[gi]);
        row[320 + t] = vmn;
        row[384 + t] = vsm / fmaxf(vcnt, 1.0f);
        row[448 + t] = vsm;
        row[512 + t] = vmx;

        row[t] = g_in[gi * D + t];
    }
    __syncthreads();

    for (int j = t; j < n_hid; j += blockDim.x) {
        float acc = b1[j];
        #pragma unroll 8
        for (int k = 0; k < n_in; ++k) acc = fmaf(row[k], W1[k * n_hid + j], acc);
        h[j] = fmaxf(acc, 0.0f);
    }
    __syncthreads();

    for (int j = t; j < n_out; j += blockDim.x) {
        float acc = b2[j];
        #pragma unroll 8
        for (int k = 0; k < n_hid; ++k) acc = fmaf(h[k], W2[k * n_out + j], acc);
        out[gi * n_out + j] = acc;
    }
}

extern "C" void kernel_launch(void* const* d_in, const int* in_sizes, int n_in_args,
                              void* d_out, int out_size, void* d_ws, size_t ws_size,
                              hipStream_t stream) {
    const float* v_attr    = (const float*)d_in[0];
    const int*   edge_pair = (const int*)d_in[1];   // [2, E]; row 0 = src
    const float* e_attr    = (const float*)d_in[2];
    const float* g_in      = (const float*)d_in[3];
    const int*   batch     = (const int*)d_in[4];
    const float* W1        = (const float*)d_in[5];
    const float* b1        = (const float*)d_in[6];
    const float* W2        = (const float*)d_in[7];
    const float* b2        = (const float*)d_in[8];

    int N  = in_sizes[4];
    int E  = in_sizes[1] / 2;
    int nh = in_sizes[6];            // 256
    int no = in_sizes[8];            // 64
    int ni = in_sizes[5] / nh;       // 576

    // ---- ws bump allocation (256B aligned) ----
    char* p = (char*)d_ws;
    auto alloc = [&](size_t bytes) {
        char* r = p;
        p += (bytes + 255) & ~(size_t)255;
        return r;
    };
    unsigned char* eseg   = (unsigned char*)alloc((size_t)E);
    unsigned*      counts = (unsigned*)alloc((size_t)G_MAX * NB * 4);
    unsigned*      gtot   = (unsigned*)alloc((size_t)G_MAX * 4);
    int*           cbase  = (int*)alloc((size_t)(G_MAX + 1) * 4);
    int*           vstart = (int*)alloc((size_t)(G_MAX + 1) * 4);
    int*           s_eid  = (int*)alloc((size_t)E * 4);
    float*         pe_min = (float*)alloc((size_t)G_MAX * EBPS * D * 4);
    float*         pe_max = (float*)alloc((size_t)G_MAX * EBPS * D * 4);
    float*         pe_sum = (float*)alloc((size_t)G_MAX * EBPS * D * 4);
    float*         pv_min = (float*)alloc((size_t)G_MAX * VBPS * D * 4);
    float*         pv_max = (float*)alloc((size_t)G_MAX * VBPS * D * 4);
    float*         pv_sum = (float*)alloc((size_t)G_MAX * VBPS * D * 4);

    k_eseg_hist<<<NB, 256, 0, stream>>>(edge_pair, batch, E, eseg, counts);
    k_scan_counts<<<G_MAX, 256, 0, stream>>>(counts, gtot);
    k_bounds<<<1, 256, 0, stream>>>(gtot, batch, N, cbase, vstart);
    k_scatter<<<NB, 256, 0, stream>>>(eseg, counts, cbase, E, s_eid);

    // combined edge + vertex gather (edges: via sorted id list; vertices: contiguous)
    k_gather_stats<<<G_MAX * EBPS + G_MAX * VBPS, 256, 0, stream>>>(
        e_attr, s_eid, cbase, v_attr, vstart,
        pe_min, pe_max, pe_sum, pv_min, pv_max, pv_sum);

    k_finalize_mlp<<<G_MAX, 256, 0, stream>>>(g_in,
        pe_min, pe_max, pe_sum, pv_min, pv_max, pv_sum,
        cbase, vstart, W1, b1, W2, b2,
        (float*)d_out, ni, nh, no);
}

// Round 7
// 127.699 us; speedup vs baseline: 4.5524x; 1.0518x over previous
//
#include <hip/hip_runtime.h>
#include <math.h>

#define G_MAX 128
#define D 64
#define NB 1024         // blocks for hist/scatter chunking
#define EBPS 16         // edge-gather blocks per graph  (power of 2)
#define EBPS_SHIFT 4
#define VBPS 4          // vertex-gather blocks per graph (power of 2)
#define VBPS_SHIFT 2
#define WPB 4           // waves per 256-thread block
#define UNR 8           // rows in flight per lane in the gather

typedef float vfloat4 __attribute__((ext_vector_type(4)));

__device__ __forceinline__ float4 ntload4(const float* p) {
    vfloat4 v = __builtin_nontemporal_load(reinterpret_cast<const vfloat4*>(p));
    return make_float4(v.x, v.y, v.z, v.w);
}

// ---------------- K1: edge segment ids + per-block histogram ----------------
__global__ __launch_bounds__(256) void k_eseg_hist(
    const int* __restrict__ src, const int* __restrict__ batch, int E,
    unsigned char* __restrict__ eseg, unsigned* __restrict__ counts /*[G_MAX][NB]*/)
{
    __shared__ unsigned hist[G_MAX];
    for (int i = threadIdx.x; i < G_MAX; i += blockDim.x) hist[i] = 0u;
    __syncthreads();
    int chunk = (E + NB - 1) / NB;
    int begin = blockIdx.x * chunk;
    int end   = min(E, begin + chunk);
    for (int e = begin + threadIdx.x; e < end; e += blockDim.x) {
        int g = batch[src[e]];
        eseg[e] = (unsigned char)g;
        atomicAdd(&hist[g], 1u);
    }
    __syncthreads();
    for (int i = threadIdx.x; i < G_MAX; i += blockDim.x)
        counts[(size_t)i * NB + blockIdx.x] = hist[i];
}

// ------------- K2a: per-graph exclusive scan of NB block counts -------------
__global__ __launch_bounds__(256) void k_scan_counts(
    unsigned* __restrict__ counts, unsigned* __restrict__ gtot)
{
    __shared__ unsigned s[256];
    unsigned* c = counts + (size_t)blockIdx.x * NB;
    int t = threadIdx.x;
    unsigned v0 = c[4*t], v1 = c[4*t+1], v2 = c[4*t+2], v3 = c[4*t+3];
    s[t] = v0 + v1 + v2 + v3;
    __syncthreads();
    for (int off = 1; off < 256; off <<= 1) {
        unsigned x = (t >= off) ? s[t - off] : 0u;
        __syncthreads();
        s[t] += x;
        __syncthreads();
    }
    unsigned base = (t > 0) ? s[t - 1] : 0u;
    c[4*t]   = base;
    c[4*t+1] = base + v0;
    c[4*t+2] = base + v0 + v1;
    c[4*t+3] = base + v0 + v1 + v2;
    if (t == 255) gtot[blockIdx.x] = s[255];
}

// ---- K2b: graph bucket bases (cbase) + vertex ranges via binary search ----
__global__ __launch_bounds__(256) void k_bounds(
    const unsigned* __restrict__ gtot, const int* __restrict__ batch, int N,
    int* __restrict__ cbase, int* __restrict__ vstart)
{
    int t = threadIdx.x;
    if (t == 0) {
        int acc = 0;
        for (int g = 0; g < G_MAX; ++g) { cbase[g] = acc; acc += (int)gtot[g]; }
        cbase[G_MAX] = acc;
    }
    if (t <= G_MAX) {
        int lo = 0, hi = N;
        while (lo < hi) {
            int mid = (lo + hi) >> 1;
            if (batch[mid] < t) lo = mid + 1; else hi = mid;
        }
        vstart[t] = lo;
    }
}

// ---------------- K3: race-free scatter into per-graph buckets --------------
__global__ __launch_bounds__(256) void k_scatter(
    const unsigned char* __restrict__ eseg, const unsigned* __restrict__ counts,
    const int* __restrict__ cbase, int E, int* __restrict__ sorted_eid)
{
    __shared__ unsigned lcur[G_MAX];
    for (int i = threadIdx.x; i < G_MAX; i += blockDim.x)
        lcur[i] = (unsigned)cbase[i] + counts[(size_t)i * NB + blockIdx.x];
    __syncthreads();
    int chunk = (E + NB - 1) / NB;
    int begin = blockIdx.x * chunk;
    int end   = min(E, begin + chunk);
    for (int e = begin + threadIdx.x; e < end; e += blockDim.x) {
        int g = eseg[e];
        unsigned pos = atomicAdd(&lcur[g], 1u);
        sorted_eid[pos] = e;
    }
}

// ---------------- K4: combined register-accumulated gather reduction --------
__device__ __forceinline__ float4 f4shfl_xor(float4 v, int m) {
    return make_float4(__shfl_xor(v.x, m, 64), __shfl_xor(v.y, m, 64),
                       __shfl_xor(v.z, m, 64), __shfl_xor(v.w, m, 64));
}
__device__ __forceinline__ float4 f4add(float4 a, float4 b) {
    return make_float4(a.x + b.x, a.y + b.y, a.z + b.z, a.w + b.w);
}
__device__ __forceinline__ void acc4(float4 v, float4& mn, float4& mx, float4& sm) {
    mn.x = fminf(mn.x, v.x); mn.y = fminf(mn.y, v.y); mn.z = fminf(mn.z, v.z); mn.w = fminf(mn.w, v.w);
    mx.x = fmaxf(mx.x, v.x); mx.y = fmaxf(mx.y, v.y); mx.z = fmaxf(mx.z, v.z); mx.w = fmaxf(mx.w, v.w);
    sm.x += v.x; sm.y += v.y; sm.z += v.z; sm.w += v.w;
}

__global__ __launch_bounds__(256) void k_gather_stats(
    const float* __restrict__ e_attr_, const int* __restrict__ s_eid,
    const int* __restrict__ cbase,
    const float* __restrict__ v_attr_, const int* __restrict__ vstart,
    float* __restrict__ pe_min, float* __restrict__ pe_max, float* __restrict__ pe_sum,
    float* __restrict__ pv_min, float* __restrict__ pv_max, float* __restrict__ pv_sum)
{
    __shared__ float lmin[WPB][D], lmax[WPB][D], lsum[WPB][D];
    const int b = blockIdx.x;
    const bool isE = (b < G_MAX * EBPS);
    const float* attr  = isE ? e_attr_ : v_attr_;
    const int*  idx    = isE ? s_eid : nullptr;
    const int*  bounds = isE ? cbase : vstart;
    float* pmin = isE ? pe_min : pv_min;
    float* pmax = isE ? pe_max : pv_max;
    float* psum = isE ? pe_sum : pv_sum;
    const int bid   = isE ? b : (b - G_MAX * EBPS);
    const int shift = isE ? EBPS_SHIFT : VBPS_SHIFT;
    const int bps   = 1 << shift;
    const int g     = bid >> shift;
    const int sub   = bid & (bps - 1);

    const int start = bounds[g], end = bounds[g + 1];
    const int lane = threadIdx.x & 63, w = threadIdx.x >> 6;
    const int q = lane >> 4;          // which of 4 row streams this lane covers
    const int p = lane & 15;          // 4-feature chunk within row
    const int wg = sub * WPB + w;     // global wave index within this graph
    const int stride = bps * WPB * (4 * UNR); // rows per wave per iteration

    float4 mn = make_float4(INFINITY, INFINITY, INFINITY, INFINITY);
    float4 mx = make_float4(-INFINITY, -INFINITY, -INFINITY, -INFINITY);
    float4 sm = make_float4(0.f, 0.f, 0.f, 0.f);

    for (int e = start + wg * (4 * UNR) + q; e < end; e += stride) {
        int  rid[UNR];
        bool ok[UNR];
        #pragma unroll
        for (int j = 0; j < UNR; ++j) {
            int ej = e + 4 * j;
            ok[j]  = ej < end;                       // ok[0] always true
            rid[j] = ok[j] ? (idx ? idx[ej] : ej) : (idx ? idx[e] : e);
        }
        float4 v[UNR];
        #pragma unroll
        for (int j = 0; j < UNR; ++j)
            v[j] = ntload4(&attr[(size_t)rid[j] * D + p * 4]);
        #pragma unroll
        for (int j = 0; j < UNR; ++j)
            if (ok[j]) acc4(v[j], mn, mx, sm);
    }

    // reduce the 4 q-groups (row streams) down to q==0 lanes
    float4 o;
    o = f4shfl_xor(mn, 16);
    mn.x = fminf(mn.x, o.x); mn.y = fminf(mn.y, o.y); mn.z = fminf(mn.z, o.z); mn.w = fminf(mn.w, o.w);
    o = f4shfl_xor(mn, 32);
    mn.x = fminf(mn.x, o.x); mn.y = fminf(mn.y, o.y); mn.z = fminf(mn.z, o.z); mn.w = fminf(mn.w, o.w);
    o = f4shfl_xor(mx, 16);
    mx.x = fmaxf(mx.x, o.x); mx.y = fmaxf(mx.y, o.y); mx.z = fmaxf(mx.z, o.z); mx.w = fmaxf(mx.w, o.w);
    o = f4shfl_xor(mx, 32);
    mx.x = fmaxf(mx.x, o.x); mx.y = fmaxf(mx.y, o.y); mx.z = fmaxf(mx.z, o.z); mx.w = fmaxf(mx.w, o.w);
    sm = f4add(sm, f4shfl_xor(sm, 16));
    sm = f4add(sm, f4shfl_xor(sm, 32));

    if (q == 0) {
        lmin[w][p*4+0] = mn.x; lmin[w][p*4+1] = mn.y; lmin[w][p*4+2] = mn.z; lmin[w][p*4+3] = mn.w;
        lmax[w][p*4+0] = mx.x; lmax[w][p*4+1] = mx.y; lmax[w][p*4+2] = mx.z; lmax[w][p*4+3] = mx.w;
        lsum[w][p*4+0] = sm.x; lsum[w][p*4+1] = sm.y; lsum[w][p*4+2] = sm.z; lsum[w][p*4+3] = sm.w;
    }
    __syncthreads();
    int t = threadIdx.x;
    if (t < D) {
        float a  = fminf(fminf(lmin[0][t], lmin[1][t]), fminf(lmin[2][t], lmin[3][t]));
        float b2 = fmaxf(fmaxf(lmax[0][t], lmax[1][t]), fmaxf(lmax[2][t], lmax[3][t]));
        float c  = lsum[0][t] + lsum[1][t] + lsum[2][t] + lsum[3][t];
        size_t o2 = ((size_t)g * bps + sub) * D + t;
        pmin[o2] = a; pmax[o2] = b2; psum[o2] = c;
    }
}

// ---------------- K5: combine partials -> 576-row -> MLP --------------------
__global__ __launch_bounds__(256) void k_finalize_mlp(
    const float* __restrict__ g_in,
    const float* __restrict__ pe_min, const float* __restrict__ pe_max, const float* __restrict__ pe_sum,
    const float* __restrict__ pv_min, const float* __restrict__ pv_max, const float* __restrict__ pv_sum,
    const int* __restrict__ cbase, const int* __restrict__ vstart,
    const float* __restrict__ W1, const float* __restrict__ b1,
    const float* __restrict__ W2, const float* __restrict__ b2,
    float* __restrict__ out, int n_in, int n_hid, int n_out)
{
    __shared__ float row[576];
    __shared__ float h[256];
    int gi = blockIdx.x;
    int t = threadIdx.x;

    if (t < D) {
        float mn = INFINITY, mx = -INFINITY, sm = 0.f;
        #pragma unroll 8
        for (int s = 0; s < EBPS; ++s) {
            size_t o = ((size_t)gi * EBPS + s) * D + t;
            mn = fminf(mn, pe_min[o]); mx = fmaxf(mx, pe_max[o]); sm += pe_sum[o];
        }
        float cnt = (float)(cbase[gi + 1] - cbase[gi]);
        row[64 + t]  = mn;
        row[128 + t] = sm / fmaxf(cnt, 1.0f);
        row[192 + t] = sm;
        row[256 + t] = mx;

        float vmn = INFINITY, vmx = -INFINITY, vsm = 0.f;
        #pragma unroll
        for (int s = 0; s < VBPS; ++s) {
            size_t o = ((size_t)gi * VBPS + s) * D + t;
            vmn = fminf(vmn, pv_min[o]); vmx = fmaxf(vmx, pv_max[o]); vsm += pv_sum[o];
        }
        float vcnt = (float)(vstart[gi + 1] - vstart[gi]);
        row[320 + t] = vmn;
        row[384 + t] = vsm / fmaxf(vcnt, 1.0f);
        row[448 + t] = vsm;
        row[512 + t] = vmx;

        row[t] = g_in[gi * D + t];
    }
    __syncthreads();

    for (int j = t; j < n_hid; j += blockDim.x) {
        float acc = b1[j];
        #pragma unroll 8
        for (int k = 0; k < n_in; ++k) acc = fmaf(row[k], W1[k * n_hid + j], acc);
        h[j] = fmaxf(acc, 0.0f);
    }
    __syncthreads();

    for (int j = t; j < n_out; j += blockDim.x) {
        float acc = b2[j];
        #pragma unroll 8
        for (int k = 0; k < n_hid; ++k) acc = fmaf(h[k], W2[k * n_out + j], acc);
        out[gi * n_out + j] = acc;
    }
}

extern "C" void kernel_launch(void* const* d_in, const int* in_sizes, int n_in_args,
                              void* d_out, int out_size, void* d_ws, size_t ws_size,
                              hipStream_t stream) {
    const float* v_attr    = (const float*)d_in[0];
    const int*   edge_pair = (const int*)d_in[1];   // [2, E]; row 0 = src
    const float* e_attr    = (const float*)d_in[2];
    const float* g_in      = (const float*)d_in[3];
    const int*   batch     = (const int*)d_in[4];
    const float* W1        = (const float*)d_in[5];
    const float* b1        = (const float*)d_in[6];
    const float* W2        = (const float*)d_in[7];
    const float* b2        = (const float*)d_in[8];

    int N  = in_sizes[4];
    int E  = in_sizes[1] / 2;
    int nh = in_sizes[6];            // 256
    int no = in_sizes[8];            // 64
    int ni = in_sizes[5] / nh;       // 576

    // ---- ws bump allocation (256B aligned) ----
    char* p = (char*)d_ws;
    auto alloc = [&](size_t bytes) {
        char* r = p;
        p += (bytes + 255) & ~(size_t)255;
        return r;
    };
    unsigned char* eseg   = (unsigned char*)alloc((size_t)E);
    unsigned*      counts = (unsigned*)alloc((size_t)G_MAX * NB * 4);
    unsigned*      gtot   = (unsigned*)alloc((size_t)G_MAX * 4);
    int*           cbase  = (int*)alloc((size_t)(G_MAX + 1) * 4);
    int*           vstart = (int*)alloc((size_t)(G_MAX + 1) * 4);
    int*           s_eid  = (int*)alloc((size_t)E * 4);
    float*         pe_min = (float*)alloc((size_t)G_MAX * EBPS * D * 4);
    float*         pe_max = (float*)alloc((size_t)G_MAX * EBPS * D * 4);
    float*         pe_sum = (float*)alloc((size_t)G_MAX * EBPS * D * 4);
    float*         pv_min = (float*)alloc((size_t)G_MAX * VBPS * D * 4);
    float*         pv_max = (float*)alloc((size_t)G_MAX * VBPS * D * 4);
    float*         pv_sum = (float*)alloc((size_t)G_MAX * VBPS * D * 4);

    k_eseg_hist<<<NB, 256, 0, stream>>>(edge_pair, batch, E, eseg, counts);
    k_scan_counts<<<G_MAX, 256, 0, stream>>>(counts, gtot);
    k_bounds<<<1, 256, 0, stream>>>(gtot, batch, N, cbase, vstart);
    k_scatter<<<NB, 256, 0, stream>>>(eseg, counts, cbase, E, s_eid);

    // combined edge + vertex gather (edges: via sorted id list; vertices: contiguous)
    k_gather_stats<<<G_MAX * EBPS + G_MAX * VBPS, 256, 0, stream>>>(
        e_attr, s_eid, cbase, v_attr, vstart,
        pe_min, pe_max, pe_sum, pv_min, pv_max, pv_sum);

    k_finalize_mlp<<<G_MAX, 256, 0, stream>>>(g_in,
        pe_min, pe_max, pe_sum, pv_min, pv_max, pv_sum,
        cbase, vstart, W1, b1, W2, b2,
        (float*)d_out, ni, nh, no);
}